// Round 11
// baseline (43.307 us; speedup 1.0000x reference)
//
#include <hip/hip_runtime.h>
#include <hip/hip_bf16.h>
#include <hip/hip_fp16.h>

typedef __attribute__((ext_vector_type(8))) short bf16x8;
typedef __attribute__((ext_vector_type(4))) float f32x4;
typedef __attribute__((ext_vector_type(4))) int   i32x4;

#define O_TOTAL 8192
#define I_TOTAL 8192
#define ROW_I32 4096       // int32 per weight row
#define NBLOCKS 256        // 32-wide k-blocks per row
#define OUT_N   (16 * O_TOTAL)

typedef __attribute__((address_space(1))) const void GASV;
typedef __attribute__((address_space(3))) void LASV;

static __device__ __forceinline__ short f2bf(float f) {
    union { __hip_bfloat16 b; short s; } u;
    u.b = __float2bfloat16(f);
    return u.s;
}

static __device__ __forceinline__ float bf2f(unsigned short s) {
    union { unsigned int u; float f; } v;
    v.u = ((unsigned int)s) << 16;
    return v.f;
}

static __device__ __forceinline__ int sniff_fmt(const void* wn) {
    const unsigned int* w32 = (const unsigned int*)wn;
    int cntLo = 0, cntHi = 0;
    #pragma unroll
    for (int i = 0; i < 16; ++i) {
        unsigned int ww = w32[i];
        unsigned int lo = ww & 0xFFFFu, hi = ww >> 16;
        if (lo >= 0x3980u && lo < 0x3F80u) cntLo++;
        if (hi >= 0x3C00u) cntHi++;
    }
    return (cntLo >= 12) ? 1 : (cntHi >= 12 ? 0 : 2); // 0=f32 1=bf16 2=f16
}

static __device__ __forceinline__ float decode_norm(const void* wn, int idx, int fmt) {
    if (fmt == 0) return ((const float*)wn)[idx];
    if (fmt == 1) return bf2f(((const unsigned short*)wn)[idx]);
    return __half2float(((const __half*)wn)[idx]);
}

// ---- kernel 0: x fp32 -> bf16 bits ----
__global__ __launch_bounds__(256)
void xcvt_kernel(const float* __restrict__ x, short* __restrict__ xb)
{
    const int i = (blockIdx.x * 256 + threadIdx.x) * 4;
    f32x4 v = *(const f32x4*)(x + i);
    union { short s[4]; long long q; } p;
    p.s[0] = f2bf(v[0]); p.s[1] = f2bf(v[1]); p.s[2] = f2bf(v[2]); p.s[3] = f2bf(v[3]);
    *(long long*)(xb + i) = p.q;
}

// ---- kernel A: split-K partial GEMM. grid = 512 otiles x 4 k-quarters ----
__global__ __launch_bounds__(256, 8)
void gemm_part(const short* __restrict__ xb,
               const int* __restrict__ wq,
               const void* __restrict__ wn,
               float* __restrict__ part)     // [4][16][8192] f32
{
    const int tid  = threadIdx.x;
    const int w    = tid >> 6;             // wave 0..3
    const int lane = tid & 63;
    const int otile = blockIdx.x >> 2;     // 0..511
    const int q     = blockIdx.x & 3;      // k-quarter 0..3
    const int o0   = otile * 16;
    const int ph   = (otile * 5) & 15;     // per-otile circular k-phase

    const int fmt = sniff_fmt(wn);

    __shared__ float nlds[64];             // this quarter's norms
    __shared__ float red[4][256];
    if (tid < 64)
        nlds[tid] = decode_norm(wn, otile * NBLOCKS + q * 64 + tid, fmt);
    __syncthreads();

    const int col = lane & 15;             // B col / A row (m)
    const int kg  = lane >> 4;             // 0..3
    const int kb0 = q * 64 + w * 16;       // global k-block base for this wave

    const int*   wrow = wq + (size_t)(o0 + col) * ROW_I32 + kb0 * 16 + kg * 4;
    const short* xrow = xb + (size_t)col * I_TOTAL + kb0 * 32 + kg * 8;

    f32x4 acc = {0.f, 0.f, 0.f, 0.f};

    // depth-2 register ring over 16 k-blocks (all indices static under unroll)
    i32x4  pv[2];
    bf16x8 xa[2];
    pv[0] = *(const i32x4*)(wrow + (size_t)ph * 16);
    xa[0] = *(const bf16x8*)(xrow + (size_t)ph * 32);

    #pragma unroll
    for (int s = 0; s < 16; ++s) {
        const int d  = s & 1;
        const int bs = (s + ph) & 15;      // within-quarter k-block (circular)
        if (s + 1 < 16) {
            const int bn = (s + 1 + ph) & 15;
            pv[d ^ 1] = *(const i32x4*)(wrow + (size_t)bn * 16);
            xa[d ^ 1] = *(const bf16x8*)(xrow + (size_t)bn * 32);
        }
        const float nf = nlds[w * 16 + bs];
        const float sc = nf * (2.0f / 15.0f);
        bf16x8 bfrag;
        #pragma unroll
        for (int c = 0; c < 4; ++c) {
            int v = pv[d][c];
            bfrag[2*c]   = f2bf((float)(v & 15)        * sc - nf);
            bfrag[2*c+1] = f2bf((float)((v >> 4) & 15) * sc - nf);
        }
        acc = __builtin_amdgcn_mfma_f32_16x16x32_bf16(xa[d], bfrag, acc, 0, 0, 0);
    }

    // cross-wave reduction (4 waves) -> partial [q][m][oc]
    *(f32x4*)&red[w][lane * 4] = acc;
    __syncthreads();

    if (tid < 256) {
        float s = red[0][tid] + red[1][tid] + red[2][tid] + red[3][tid];
        const int l = tid >> 2;
        const int r = tid & 3;
        const int m  = ((l >> 4) << 2) + r;    // C row = (lane>>4)*4 + reg
        const int oc = o0 + (l & 15);          // C col = lane&15
        part[(size_t)q * OUT_N + (size_t)m * O_TOTAL + oc] = s;
    }
}

// ---- kernel B: sum 4 partials + bias ----
__global__ __launch_bounds__(256)
void reduce_k(const float* __restrict__ part, const float* __restrict__ bias,
              float* __restrict__ out)
{
    const int i = (blockIdx.x * 256 + threadIdx.x) * 4;
    f32x4 a = *(const f32x4*)(part + i);
    f32x4 b = *(const f32x4*)(part + OUT_N + i);
    f32x4 c = *(const f32x4*)(part + 2 * OUT_N + i);
    f32x4 d = *(const f32x4*)(part + 3 * OUT_N + i);
    f32x4 bs = *(const f32x4*)(bias + (i & (O_TOTAL - 1)));
    f32x4 r = a + b + c + d + bs;
    *(f32x4*)(out + i) = r;
}

// ==== fallback: R7 kernel (known 34.1 us) if d_ws is too small ====
#define NWAVES  8
#define NSS     32
__global__ __launch_bounds__(512, 6)
void linq4_fb(const short* __restrict__ xb, const int* __restrict__ wq,
              const void* __restrict__ wn, const float* __restrict__ bias,
              float* __restrict__ out)
{
    const int tid  = threadIdx.x;
    const int w    = tid >> 6;
    const int lane = tid & 63;
    const int otile = blockIdx.x;
    const int o0   = otile * 16;
    const int phase = (otile * 7) & (NSS - 1);

    const int fmt = sniff_fmt(wn);

    __shared__ int   w_lds[2][2048];
    __shared__ short x_lds[2][4096];
    __shared__ float nlds[NBLOCKS];
    __shared__ float red[NWAVES][256];

    if (tid < NBLOCKS)
        nlds[tid] = decode_norm(wn, otile * NBLOCKS + tid, fmt);

    const int r_st  = 2 * w + (lane >> 5);
    const int jj    = (lane & 31) ^ (r_st & 7);
    const int* gw_base   = wq + (size_t)(o0 + r_st) * ROW_I32 + jj * 4;
    const short* gx_base = xb + (size_t)r_st * I_TOTAL + jj * 8;

    const int col = lane & 15;
    const int kg  = lane >> 4;
    const int j   = w * 4 + kg;
    const int t   = j ^ (col & 7);
    const int ldsoff = col * 128 + t * 4;
    const int xldoff = col * 256 + t * 8;

    f32x4 acc = {0.f, 0.f, 0.f, 0.f};

    __builtin_amdgcn_global_load_lds((GASV*)(gw_base + phase * 128),
                                     (LASV*)(&w_lds[0][w * 256]), 16, 0, 0);
    __builtin_amdgcn_global_load_lds((GASV*)(gx_base + phase * 256),
                                     (LASV*)(&x_lds[0][w * 512]), 16, 0, 0);
    __syncthreads();

    for (int S = 0; S < NSS; ++S) {
        const int cur = S & 1;
        const int Sp  = (S + phase) & (NSS - 1);
        if (S + 1 < NSS) {
            const int Spn = (S + 1 + phase) & (NSS - 1);
            const int nxt = cur ^ 1;
            __builtin_amdgcn_global_load_lds((GASV*)(gw_base + Spn * 128),
                                             (LASV*)(&w_lds[nxt][w * 256]), 16, 0, 0);
            __builtin_amdgcn_global_load_lds((GASV*)(gx_base + Spn * 256),
                                             (LASV*)(&x_lds[nxt][w * 512]), 16, 0, 0);
        }
        i32x4  pv = *(const i32x4*)(&w_lds[cur][ldsoff]);
        bf16x8 xa = *(const bf16x8*)(&x_lds[cur][xldoff]);
        const float nf = nlds[Sp * 8 + w];
        const float sc = nf * (2.0f / 15.0f);
        bf16x8 bfrag;
        #pragma unroll
        for (int c = 0; c < 4; ++c) {
            int v = pv[c];
            bfrag[2*c]   = f2bf((float)(v & 15)        * sc - nf);
            bfrag[2*c+1] = f2bf((float)((v >> 4) & 15) * sc - nf);
        }
        acc = __builtin_amdgcn_mfma_f32_16x16x32_bf16(xa, bfrag, acc, 0, 0, 0);
        __syncthreads();
    }

    *(f32x4*)&red[w][lane * 4] = acc;
    __syncthreads();

    if (tid < 256) {
        float s = 0.f;
        #pragma unroll
        for (int qq = 0; qq < NWAVES; ++qq) s += red[qq][tid];
        const int l = tid >> 2;
        const int r = tid & 3;
        const int m  = ((l >> 4) << 2) + r;
        const int oc = o0 + (l & 15);
        out[(size_t)m * O_TOTAL + oc] = s + bias[oc];
    }
}

extern "C" void kernel_launch(void* const* d_in, const int* in_sizes, int n_in,
                              void* d_out, int out_size, void* d_ws, size_t ws_size,
                              hipStream_t stream) {
    const float* x    = (const float*)d_in[0];
    const int*   wq   = (const int*)d_in[1];
    const void*  wn   = (const void*)d_in[2];
    const float* bias = (const float*)d_in[3];
    float* out = (float*)d_out;

    short* xb = (short*)d_ws;                              // 256 KB
    const size_t xb_bytes   = (size_t)16 * I_TOTAL * 2;
    const size_t part_bytes = (size_t)4 * OUT_N * 4;       // 2 MB

    hipLaunchKernelGGL(xcvt_kernel, dim3(16 * I_TOTAL / 4 / 256), dim3(256), 0, stream, x, xb);

    if (ws_size >= xb_bytes + part_bytes) {
        float* part = (float*)((char*)d_ws + xb_bytes);
        hipLaunchKernelGGL(gemm_part, dim3(512 * 4), dim3(256), 0, stream,
                           (const short*)xb, wq, wn, part);
        hipLaunchKernelGGL(reduce_k, dim3(OUT_N / 4 / 256), dim3(256), 0, stream,
                           (const float*)part, bias, out);
    } else {
        hipLaunchKernelGGL(linq4_fb, dim3(O_TOTAL / 16), dim3(512), 0, stream,
                           (const short*)xb, wq, wn, bias, out);
    }
}

// Round 12
// 35.037 us; speedup vs baseline: 1.2360x; 1.2360x over previous
//
#include <hip/hip_runtime.h>
#include <hip/hip_bf16.h>
#include <hip/hip_fp16.h>

typedef __attribute__((ext_vector_type(8))) short bf16x8;
typedef __attribute__((ext_vector_type(4))) float f32x4;
typedef __attribute__((ext_vector_type(4))) int   i32x4;

#define O_TOTAL 8192
#define I_TOTAL 8192
#define ROW_I32 4096       // int32 per weight row
#define NBLOCKS 256        // 32-wide k-blocks per row
#define OUT_N   (16 * O_TOTAL)
#define NSSH    16         // supersteps per half-K chain

typedef __attribute__((address_space(1))) const void GASV;
typedef __attribute__((address_space(3))) void LASV;

static __device__ __forceinline__ short f2bf(float f) {
    union { __hip_bfloat16 b; short s; } u;
    u.b = __float2bfloat16(f);
    return u.s;
}

static __device__ __forceinline__ float bf2f(unsigned short s) {
    union { unsigned int u; float f; } v;
    v.u = ((unsigned int)s) << 16;
    return v.f;
}

static __device__ __forceinline__ int sniff_fmt(const void* wn) {
    const unsigned int* w32 = (const unsigned int*)wn;
    int cntLo = 0, cntHi = 0;
    #pragma unroll
    for (int i = 0; i < 16; ++i) {
        unsigned int ww = w32[i];
        unsigned int lo = ww & 0xFFFFu, hi = ww >> 16;
        if (lo >= 0x3980u && lo < 0x3F80u) cntLo++;
        if (hi >= 0x3C00u) cntHi++;
    }
    return (cntLo >= 12) ? 1 : (cntHi >= 12 ? 0 : 2); // 0=f32 1=bf16 2=f16
}

static __device__ __forceinline__ float decode_norm(const void* wn, int idx, int fmt) {
    if (fmt == 0) return ((const float*)wn)[idx];
    if (fmt == 1) return bf2f(((const unsigned short*)wn)[idx]);
    return __half2float(((const __half*)wn)[idx]);
}

// ---- kernel 0: x fp32 -> bf16 bits ----
__global__ __launch_bounds__(256)
void xcvt_kernel(const float* __restrict__ x, short* __restrict__ xb)
{
    const int i = (blockIdx.x * 256 + threadIdx.x) * 4;
    f32x4 v = *(const f32x4*)(x + i);
    union { short s[4]; long long q; } p;
    p.s[0] = f2bf(v[0]); p.s[1] = f2bf(v[1]); p.s[2] = f2bf(v[2]); p.s[3] = f2bf(v[3]);
    *(long long*)(xb + i) = p.q;
}

// ---- kernel A: R7 structure, split-K x2. grid = 512 otiles x 2 k-halves ----
__global__ __launch_bounds__(512, 8)
void gemm_h(const short* __restrict__ xb,
            const int* __restrict__ wq,
            const void* __restrict__ wn,
            float* __restrict__ part)      // [2][16][8192] f32
{
    const int tid  = threadIdx.x;
    const int w    = tid >> 6;             // wave 0..7
    const int lane = tid & 63;
    const int bid  = blockIdx.x;
    const int otile = bid >> 1;            // 0..511
    const int kh    = bid & 1;             // k-half
    const int o0   = otile * 16;
    const int phase = (otile * 7 + kh * 5) & (NSSH - 1);

    const int fmt = sniff_fmt(wn);

    // 33 KB LDS -> 4 blocks/CU; reduction buffer aliases w_lds after the loop
    __shared__ int   w_lds[2][2048];       // 2 x 8KB
    __shared__ short x_lds[2][4096];       // 2 x 8KB
    __shared__ float nlds[128];            // this half's norms

    if (tid < 128)
        nlds[tid] = decode_norm(wn, otile * NBLOCKS + kh * 128 + tid, fmt);

    // staging geometry (R7 verbatim, + kh offset)
    const int r_st  = 2 * w + (lane >> 5);
    const int jj    = (lane & 31) ^ (r_st & 7);    // involution pre-swizzle
    const int* gw_base   = wq + (size_t)(o0 + r_st) * ROW_I32 + kh * 2048 + jj * 4;
    const short* gx_base = xb + (size_t)r_st * I_TOTAL + kh * 4096 + jj * 8;

    // consume geometry (R7 verbatim)
    const int col = lane & 15;
    const int kg  = lane >> 4;
    const int j   = w * 4 + kg;
    const int t   = j ^ (col & 7);
    const int ldsoff = col * 128 + t * 4;
    const int xldoff = col * 256 + t * 8;

    f32x4 acc = {0.f, 0.f, 0.f, 0.f};

    __builtin_amdgcn_global_load_lds((GASV*)(gw_base + phase * 128),
                                     (LASV*)(&w_lds[0][w * 256]), 16, 0, 0);
    __builtin_amdgcn_global_load_lds((GASV*)(gx_base + phase * 256),
                                     (LASV*)(&x_lds[0][w * 512]), 16, 0, 0);
    __syncthreads();   // buf0 + nlds ready

    for (int S = 0; S < NSSH; ++S) {
        const int cur = S & 1;
        const int Sp  = (S + phase) & (NSSH - 1);
        if (S + 1 < NSSH) {
            const int Spn = (S + 1 + phase) & (NSSH - 1);
            const int nxt = cur ^ 1;
            __builtin_amdgcn_global_load_lds((GASV*)(gw_base + Spn * 128),
                                             (LASV*)(&w_lds[nxt][w * 256]), 16, 0, 0);
            __builtin_amdgcn_global_load_lds((GASV*)(gx_base + Spn * 256),
                                             (LASV*)(&x_lds[nxt][w * 512]), 16, 0, 0);
        }
        i32x4  pv = *(const i32x4*)(&w_lds[cur][ldsoff]);
        bf16x8 xa = *(const bf16x8*)(&x_lds[cur][xldoff]);
        const float nf = nlds[Sp * 8 + w];
        const float sc = nf * (2.0f / 15.0f);
        bf16x8 bfrag;
        #pragma unroll
        for (int c = 0; c < 4; ++c) {
            int v = pv[c];
            bfrag[2*c]   = f2bf((float)(v & 15)        * sc - nf);
            bfrag[2*c+1] = f2bf((float)((v >> 4) & 15) * sc - nf);
        }
        acc = __builtin_amdgcn_mfma_f32_16x16x32_bf16(xa, bfrag, acc, 0, 0, 0);
        __syncthreads();
    }

    // cross-wave reduction in LDS aliased onto w_lds (loop fully done)
    float* red = (float*)&w_lds[0][0];     // 8 KB needed, 16 KB available
    *(f32x4*)&red[w * 256 + lane * 4] = acc;
    __syncthreads();

    if (tid < 256) {
        float s = 0.f;
        #pragma unroll
        for (int q = 0; q < 8; ++q) s += red[q * 256 + tid];
        const int l = tid >> 2;
        const int r = tid & 3;
        const int m  = ((l >> 4) << 2) + r;    // C row = (lane>>4)*4 + reg
        const int oc = o0 + (l & 15);          // C col = lane&15
        part[(size_t)kh * OUT_N + (size_t)m * O_TOTAL + oc] = s;
    }
}

// ---- kernel B: sum 2 partials + bias ----
__global__ __launch_bounds__(256)
void reduce2(const float* __restrict__ part, const float* __restrict__ bias,
             float* __restrict__ out)
{
    const int i = (blockIdx.x * 256 + threadIdx.x) * 4;
    f32x4 a = *(const f32x4*)(part + i);
    f32x4 b = *(const f32x4*)(part + OUT_N + i);
    f32x4 bs = *(const f32x4*)(bias + (i & (O_TOTAL - 1)));
    *(f32x4*)(out + i) = a + b + bs;
}

// ==== fallback: R7 kernel (known 34.1 us) if d_ws too small ====
#define NWAVES  8
#define NSS     32
__global__ __launch_bounds__(512, 6)
void linq4_fb(const short* __restrict__ xb, const int* __restrict__ wq,
              const void* __restrict__ wn, const float* __restrict__ bias,
              float* __restrict__ out)
{
    const int tid  = threadIdx.x;
    const int w    = tid >> 6;
    const int lane = tid & 63;
    const int otile = blockIdx.x;
    const int o0   = otile * 16;
    const int phase = (otile * 7) & (NSS - 1);

    const int fmt = sniff_fmt(wn);

    __shared__ int   w_lds[2][2048];
    __shared__ short x_lds[2][4096];
    __shared__ float nlds[NBLOCKS];
    __shared__ float red[NWAVES][256];

    if (tid < NBLOCKS)
        nlds[tid] = decode_norm(wn, otile * NBLOCKS + tid, fmt);

    const int r_st  = 2 * w + (lane >> 5);
    const int jj    = (lane & 31) ^ (r_st & 7);
    const int* gw_base   = wq + (size_t)(o0 + r_st) * ROW_I32 + jj * 4;
    const short* gx_base = xb + (size_t)r_st * I_TOTAL + jj * 8;

    const int col = lane & 15;
    const int kg  = lane >> 4;
    const int j   = w * 4 + kg;
    const int t   = j ^ (col & 7);
    const int ldsoff = col * 128 + t * 4;
    const int xldoff = col * 256 + t * 8;

    f32x4 acc = {0.f, 0.f, 0.f, 0.f};

    __builtin_amdgcn_global_load_lds((GASV*)(gw_base + phase * 128),
                                     (LASV*)(&w_lds[0][w * 256]), 16, 0, 0);
    __builtin_amdgcn_global_load_lds((GASV*)(gx_base + phase * 256),
                                     (LASV*)(&x_lds[0][w * 512]), 16, 0, 0);
    __syncthreads();

    for (int S = 0; S < NSS; ++S) {
        const int cur = S & 1;
        const int Sp  = (S + phase) & (NSS - 1);
        if (S + 1 < NSS) {
            const int Spn = (S + 1 + phase) & (NSS - 1);
            const int nxt = cur ^ 1;
            __builtin_amdgcn_global_load_lds((GASV*)(gw_base + Spn * 128),
                                             (LASV*)(&w_lds[nxt][w * 256]), 16, 0, 0);
            __builtin_amdgcn_global_load_lds((GASV*)(gx_base + Spn * 256),
                                             (LASV*)(&x_lds[nxt][w * 512]), 16, 0, 0);
        }
        i32x4  pv = *(const i32x4*)(&w_lds[cur][ldsoff]);
        bf16x8 xa = *(const bf16x8*)(&x_lds[cur][xldoff]);
        const float nf = nlds[Sp * 8 + w];
        const float sc = nf * (2.0f / 15.0f);
        bf16x8 bfrag;
        #pragma unroll
        for (int c = 0; c < 4; ++c) {
            int v = pv[c];
            bfrag[2*c]   = f2bf((float)(v & 15)        * sc - nf);
            bfrag[2*c+1] = f2bf((float)((v >> 4) & 15) * sc - nf);
        }
        acc = __builtin_amdgcn_mfma_f32_16x16x32_bf16(xa, bfrag, acc, 0, 0, 0);
        __syncthreads();
    }

    *(f32x4*)&red[w][lane * 4] = acc;
    __syncthreads();

    if (tid < 256) {
        float s = 0.f;
        #pragma unroll
        for (int qq = 0; qq < NWAVES; ++qq) s += red[qq][tid];
        const int l = tid >> 2;
        const int r = tid & 3;
        const int m  = ((l >> 4) << 2) + r;
        const int oc = o0 + (l & 15);
        out[(size_t)m * O_TOTAL + oc] = s + bias[oc];
    }
}

extern "C" void kernel_launch(void* const* d_in, const int* in_sizes, int n_in,
                              void* d_out, int out_size, void* d_ws, size_t ws_size,
                              hipStream_t stream) {
    const float* x    = (const float*)d_in[0];
    const int*   wq   = (const int*)d_in[1];
    const void*  wn   = (const void*)d_in[2];
    const float* bias = (const float*)d_in[3];
    float* out = (float*)d_out;

    short* xb = (short*)d_ws;                              // 256 KB
    const size_t xb_bytes   = (size_t)16 * I_TOTAL * 2;
    const size_t part_bytes = (size_t)2 * OUT_N * 4;       // 1 MB

    hipLaunchKernelGGL(xcvt_kernel, dim3(16 * I_TOTAL / 4 / 256), dim3(256), 0, stream, x, xb);

    if (ws_size >= xb_bytes + part_bytes) {
        float* part = (float*)((char*)d_ws + xb_bytes);
        hipLaunchKernelGGL(gemm_h, dim3(512 * 2), dim3(512), 0, stream,
                           (const short*)xb, wq, wn, part);
        hipLaunchKernelGGL(reduce2, dim3(OUT_N / 4 / 256), dim3(256), 0, stream,
                           (const float*)part, bias, out);
    } else {
        hipLaunchKernelGGL(linq4_fb, dim3(O_TOTAL / 16), dim3(512), 0, stream,
                           (const short*)xb, wq, wn, bias, out);
    }
}

// Round 13
// 34.317 us; speedup vs baseline: 1.2620x; 1.0210x over previous
//
#include <hip/hip_runtime.h>
#include <hip/hip_bf16.h>
#include <hip/hip_fp16.h>

typedef __attribute__((ext_vector_type(8))) short bf16x8;
typedef __attribute__((ext_vector_type(4))) float f32x4;
typedef __attribute__((ext_vector_type(4))) int   i32x4;

#define O_TOTAL 8192
#define I_TOTAL 8192
#define ROW_I32 4096       // int32 per weight row
#define NBLOCKS 256        // 32-wide k-blocks per row
#define NSS     32         // supersteps

typedef __attribute__((address_space(1))) const void GASV;
typedef __attribute__((address_space(3))) void LASV;

static __device__ __forceinline__ short f2bf(float f) {
    union { __hip_bfloat16 b; short s; } u;
    u.b = __float2bfloat16(f);
    return u.s;
}

static __device__ __forceinline__ float bf2f(unsigned short s) {
    union { unsigned int u; float f; } v;
    v.u = ((unsigned int)s) << 16;
    return v.f;
}

static __device__ __forceinline__ int sniff_fmt(const void* wn) {
    const unsigned int* w32 = (const unsigned int*)wn;
    int cntLo = 0, cntHi = 0;
    #pragma unroll
    for (int i = 0; i < 16; ++i) {
        unsigned int ww = w32[i];
        unsigned int lo = ww & 0xFFFFu, hi = ww >> 16;
        if (lo >= 0x3980u && lo < 0x3F80u) cntLo++;
        if (hi >= 0x3C00u) cntHi++;
    }
    return (cntLo >= 12) ? 1 : (cntHi >= 12 ? 0 : 2); // 0=f32 1=bf16 2=f16
}

static __device__ __forceinline__ float decode_norm(const void* wn, int idx, int fmt) {
    if (fmt == 0) return ((const float*)wn)[idx];
    if (fmt == 1) return bf2f(((const unsigned short*)wn)[idx]);
    return __half2float(((const __half*)wn)[idx]);
}

// ---- kernel 0: x fp32 -> bf16 bits ----
__global__ __launch_bounds__(256)
void xcvt_kernel(const float* __restrict__ x, short* __restrict__ xb)
{
    const int i = (blockIdx.x * 256 + threadIdx.x) * 4;
    f32x4 v = *(const f32x4*)(x + i);
    union { short s[4]; long long q; } p;
    p.s[0] = f2bf(v[0]); p.s[1] = f2bf(v[1]); p.s[2] = f2bf(v[2]); p.s[3] = f2bf(v[3]);
    *(long long*)(xb + i) = p.q;
}

// ---- kernel 1: wide-tile (32 o-rows) R7-structure kernel, x staged once ----
// grid = 256 blocks x 1024 threads (16 waves = 2 groups of 8)
__global__ __launch_bounds__(1024, 4)
void gemm_w(const short* __restrict__ xb,
            const int* __restrict__ wq,
            const void* __restrict__ wn,
            const float* __restrict__ bias,
            float* __restrict__ out)
{
    const int tid  = threadIdx.x;
    const int w    = tid >> 6;             // wave 0..15
    const int lane = tid & 63;
    const int grp  = w >> 3;               // 0/1: which 16-row o-tile half
    const int wg   = w & 7;                // wave within group
    const int bid  = blockIdx.x;           // 0..255
    const int o0   = bid * 32;             // 32 output rows per block
    const int phase = (bid * 7) & (NSS - 1);

    const int fmt = sniff_fmt(wn);

    // ---- LDS: 50 KB ----
    __shared__ int   w_lds[2][4096];       // 2 x 16KB: [grp 8KB][16 rows x 512B]
    __shared__ short x_lds[2][4096];       // 2 x 8KB:  [16 rows x 512B]
    __shared__ float nlds[2][256];         // 2KB: per-group norms

    if (tid < 512) {
        const int g = tid >> 8, idx = tid & 255;
        nlds[g][idx] = decode_norm(wn, (bid * 2 + g) * NBLOCKS + idx, fmt);
    }

    // ---- staging geometry (R7 verbatim per group) ----
    const int r_st = 2 * wg + (lane >> 5);         // row-in-16 staged by this lane
    const int jj   = (lane & 31) ^ (r_st & 7);     // involution pre-swizzle
    // W: global row = o0 + grp*16 + r_st
    const int* gw_base = wq + (size_t)(o0 + grp * 16 + r_st) * ROW_I32 + jj * 4; // +Sp*128
    // x: staged by group B only (rows of x = batch rows 0..15)
    const short* gx_base = xb + (size_t)r_st * I_TOTAL + jj * 8;                 // +Sp*256

    // ---- consume geometry (R7 verbatim, group-offset for W) ----
    const int col = lane & 15;             // B col within tile / A row (m)
    const int kg  = lane >> 4;             // 0..3
    const int t   = (wg * 4 + kg) ^ (col & 7);     // swizzled 16B unit
    char* wl0 = (char*)&w_lds[0][0];
    char* wl1 = (char*)&w_lds[1][0];
    char* xl0 = (char*)&x_lds[0][0];
    char* xl1 = (char*)&x_lds[1][0];
    const int woff = grp * 8192 + col * 512 + t * 16;   // byte offset in a W buffer
    const int xoff = col * 512 + t * 16;                // byte offset in an x buffer

    f32x4 acc = {0.f, 0.f, 0.f, 0.f};

    // ---- prologue: stage superstep `phase` into buffer 0 ----
    __builtin_amdgcn_global_load_lds((GASV*)(gw_base + phase * 128),
                                     (LASV*)(wl0 + grp * 8192 + wg * 1024), 16, 0, 0);
    if (grp == 1)
        __builtin_amdgcn_global_load_lds((GASV*)(gx_base + phase * 256),
                                         (LASV*)(xl0 + wg * 1024), 16, 0, 0);
    __syncthreads();   // drains vmcnt(0): buf0 + nlds ready

    for (int S = 0; S < NSS; ++S) {
        const int cur = S & 1;
        const int Sp  = (S + phase) & (NSS - 1);
        if (S + 1 < NSS) {
            const int Spn = (S + 1 + phase) & (NSS - 1);
            char* wln = cur ? wl0 : wl1;
            char* xln = cur ? xl0 : xl1;
            __builtin_amdgcn_global_load_lds((GASV*)(gw_base + Spn * 128),
                                             (LASV*)(wln + grp * 8192 + wg * 1024), 16, 0, 0);
            if (grp == 1)
                __builtin_amdgcn_global_load_lds((GASV*)(gx_base + Spn * 256),
                                                 (LASV*)(xln + wg * 1024), 16, 0, 0);
        }

        // consume: one MFMA for k-block (Sp*8 + wg), W rows of this group's tile
        char* wlc = cur ? wl1 : wl0;
        char* xlc = cur ? xl1 : xl0;
        i32x4  pv = *(const i32x4*)(wlc + woff);
        bf16x8 xa = *(const bf16x8*)(xlc + xoff);
        const float nf = nlds[grp][Sp * 8 + wg];
        const float sc = nf * (2.0f / 15.0f);

        bf16x8 bfrag;
        #pragma unroll
        for (int c = 0; c < 4; ++c) {
            int v = pv[c];
            bfrag[2*c]   = f2bf((float)(v & 15)        * sc - nf);
            bfrag[2*c+1] = f2bf((float)((v >> 4) & 15) * sc - nf);
        }
        acc = __builtin_amdgcn_mfma_f32_16x16x32_bf16(xa, bfrag, acc, 0, 0, 0);

        __syncthreads();   // reads of cur done; stage S+1 landed
    }

    // ---- per-group cross-wave reduction, aliased onto w_lds (loop done) ----
    float* red = (float*)&w_lds[0][0];     // 16 KB needed, 32 KB available
    *(f32x4*)&red[w * 256 + lane * 4] = acc;
    __syncthreads();

    if (tid < 512) {
        const int g  = tid >> 8;           // group
        const int it = tid & 255;
        float s = 0.f;
        #pragma unroll
        for (int q = 0; q < 8; ++q) s += red[(g * 8 + q) * 256 + it];
        const int l = it >> 2;             // original lane
        const int r = it & 3;              // acc register index
        const int m  = ((l >> 4) << 2) + r;        // C row = (lane>>4)*4 + reg
        const int oc = o0 + g * 16 + (l & 15);     // C col = lane&15
        out[(size_t)m * O_TOTAL + oc] = s + bias[oc];
    }
}

extern "C" void kernel_launch(void* const* d_in, const int* in_sizes, int n_in,
                              void* d_out, int out_size, void* d_ws, size_t ws_size,
                              hipStream_t stream) {
    const float* x    = (const float*)d_in[0];
    const int*   wq   = (const int*)d_in[1];
    const void*  wn   = (const void*)d_in[2];
    const float* bias = (const float*)d_in[3];
    float* out = (float*)d_out;
    short* xb  = (short*)d_ws;                  // 256 KB scratch

    hipLaunchKernelGGL(xcvt_kernel, dim3(16 * I_TOTAL / 4 / 256), dim3(256), 0, stream, x, xb);

    // 256 blocks (1/CU) x 1024 threads: 32 o-rows per block, shared x staging
    hipLaunchKernelGGL(gemm_w, dim3(O_TOTAL / 32), dim3(1024), 0, stream,
                       (const short*)xb, wq, wn, bias, out);
}